// Round 1
// baseline (147.702 us; speedup 1.0000x reference)
//
#include <hip/hip_runtime.h>

// Problem constants
#define BT_TOTAL (32 * 1024)   // B*T = 32768
#define DIM 512                // D
#define NG 8                   // G groups
#define NK 256                 // K codes per group
#define GD 64                  // group dim

#define XQ_ELEMS (BT_TOTAL * DIM)          // 16777216
#define LOSS_OFF XQ_ELEMS                  // 16777216
#define IDX_OFF (XQ_ELEMS + 1)             // 16777217

// ---------------------------------------------------------------------------
// Prep: compute c_sq[g][k] = sum_d codebooks[g][k][d]^2, and zero the loss slot
// ---------------------------------------------------------------------------
__global__ void pq_prep(const float* __restrict__ cb,
                        float* __restrict__ csq,
                        float* __restrict__ loss_slot) {
    int i = blockIdx.x * 256 + threadIdx.x;  // 0 .. 2047
    if (i == 0) *loss_slot = 0.0f;
    if (i < NG * NK) {
        const float* row = cb + (size_t)i * GD;
        float a0 = 0.f, a1 = 0.f, a2 = 0.f, a3 = 0.f;
#pragma unroll
        for (int d = 0; d < GD; d += 4) {
            a0 = fmaf(row[d + 0], row[d + 0], a0);
            a1 = fmaf(row[d + 1], row[d + 1], a1);
            a2 = fmaf(row[d + 2], row[d + 2], a2);
            a3 = fmaf(row[d + 3], row[d + 3], a3);
        }
        csq[i] = (a0 + a1) + (a2 + a3);
    }
}

// ---------------------------------------------------------------------------
// Main: one thread per (bt, g). g = blockIdx.y (wave-uniform so codebook
// loads are scalar). x row (64 f32) held in VGPRs; 256-code argmin; then
// straight-through output + idx + per-block loss partial.
// ---------------------------------------------------------------------------
__global__ __launch_bounds__(256) void pq_main(const float* __restrict__ x,
                                               const float* __restrict__ cb,
                                               const float* __restrict__ csq,
                                               float* __restrict__ out) {
    const int g = blockIdx.y;
    const int bt = blockIdx.x * 256 + threadIdx.x;

    const float* xrow = x + (size_t)bt * DIM + g * GD;
    float4 xr[16];
#pragma unroll
    for (int i = 0; i < 16; ++i) xr[i] = ((const float4*)xrow)[i];

    // x_sq = sum(x^2)
    float a0 = 0.f, a1 = 0.f, a2 = 0.f, a3 = 0.f;
#pragma unroll
    for (int i = 0; i < 16; ++i) {
        a0 = fmaf(xr[i].x, xr[i].x, a0);
        a1 = fmaf(xr[i].y, xr[i].y, a1);
        a2 = fmaf(xr[i].z, xr[i].z, a2);
        a3 = fmaf(xr[i].w, xr[i].w, a3);
    }
    const float x_sq = (a0 + a1) + (a2 + a3);

    const float* cbg = cb + (size_t)g * NK * GD;
    const float* csqg = csq + g * NK;

    float best = 3.402823466e38f;
    int bi = 0;
    for (int k = 0; k < NK; ++k) {
        const float4* c4 = (const float4*)(cbg + k * GD);
        float d0 = 0.f, d1 = 0.f, d2 = 0.f, d3 = 0.f;
#pragma unroll
        for (int i = 0; i < 16; ++i) {
            float4 c = c4[i];
            d0 = fmaf(xr[i].x, c.x, d0);
            d1 = fmaf(xr[i].y, c.y, d1);
            d2 = fmaf(xr[i].z, c.z, d2);
            d3 = fmaf(xr[i].w, c.w, d3);
        }
        float dot = (d0 + d1) + (d2 + d3);
        float dist = (x_sq + csqg[k]) - 2.0f * dot;
        if (dist < best) { best = dist; bi = k; }
    }

    // --- outputs ---
    // idx (as float; values 0..255 exact)
    out[IDX_OFF + (size_t)bt * NG + g] = (float)bi;

    // straight-through x_q = xg + (xq - xg), replicated rounding; loss partial
    const float4* q4 = (const float4*)(cbg + bi * GD);
    float4* xq_out = (float4*)(out + (size_t)bt * DIM + g * GD);
    float s0 = 0.f, s1 = 0.f, s2 = 0.f, s3 = 0.f;
#pragma unroll
    for (int i = 0; i < 16; ++i) {
        float4 q = q4[i];
        float dx = q.x - xr[i].x;
        float dy = q.y - xr[i].y;
        float dz = q.z - xr[i].z;
        float dw = q.w - xr[i].w;
        float4 o;
        o.x = xr[i].x + dx;
        o.y = xr[i].y + dy;
        o.z = xr[i].z + dz;
        o.w = xr[i].w + dw;
        xq_out[i] = o;
        s0 = fmaf(dx, dx, s0);
        s1 = fmaf(dy, dy, s1);
        s2 = fmaf(dz, dz, s2);
        s3 = fmaf(dw, dw, s3);
    }
    float part = (s0 + s1) + (s2 + s3);

    // wave reduce (64 lanes)
#pragma unroll
    for (int off = 32; off > 0; off >>= 1) part += __shfl_down(part, off);

    __shared__ float wsum[4];
    const int lane = threadIdx.x & 63;
    const int wid = threadIdx.x >> 6;
    if (lane == 0) wsum[wid] = part;
    __syncthreads();
    if (threadIdx.x == 0) {
        float bs = (wsum[0] + wsum[1]) + (wsum[2] + wsum[3]);
        // losses = 2 * sum_g mean_{B,T,gd}; mean divisor = 32768*64 = 2097152
        atomicAdd(out + LOSS_OFF, bs * (2.0f / 2097152.0f));
    }
}

extern "C" void kernel_launch(void* const* d_in, const int* in_sizes, int n_in,
                              void* d_out, int out_size, void* d_ws, size_t ws_size,
                              hipStream_t stream) {
    const float* x = (const float*)d_in[0];
    const float* cb = (const float*)d_in[1];
    float* out = (float*)d_out;
    float* csq = (float*)d_ws;  // 2048 floats = 8 KB scratch

    // prep: c_sq + zero loss slot
    pq_prep<<<dim3(8), dim3(256), 0, stream>>>(cb, csq, out + LOSS_OFF);

    // main: grid (BT/256, G), one thread per (bt, g)
    dim3 grid(BT_TOTAL / 256, NG);
    pq_main<<<grid, dim3(256), 0, stream>>>(x, cb, csq, out);
}

// Round 2
// 147.482 us; speedup vs baseline: 1.0015x; 1.0015x over previous
//
#include <hip/hip_runtime.h>

// Problem constants
#define BT_TOTAL (32 * 1024)   // B*T = 32768
#define DIM 512                // D
#define NG 8                   // G groups
#define NK 256                 // K codes per group
#define GD 64                  // group dim
#define QB 128                 // queries per block (main kernel)

#define XQ_ELEMS (BT_TOTAL * DIM)          // 16777216
#define LOSS_OFF XQ_ELEMS                  // 16777216
#define IDX_OFF (XQ_ELEMS + 1)             // 16777217

// ---------------------------------------------------------------------------
// Prep: c_sq[g][k] = sum_d cb[g][k][d]^2 (canonical stride-4 order), zero loss
// ---------------------------------------------------------------------------
__global__ void pq_prep(const float* __restrict__ cb,
                        float* __restrict__ csq,
                        float* __restrict__ loss_slot) {
    int i = blockIdx.x * 256 + threadIdx.x;  // 0 .. 2047
    if (i == 0) *loss_slot = 0.0f;
    if (i < NG * NK) {
        const float* row = cb + (size_t)i * GD;
        float a0 = 0.f, a1 = 0.f, a2 = 0.f, a3 = 0.f;
#pragma unroll
        for (int d = 0; d < GD; d += 4) {
            a0 = fmaf(row[d + 0], row[d + 0], a0);
            a1 = fmaf(row[d + 1], row[d + 1], a1);
            a2 = fmaf(row[d + 2], row[d + 2], a2);
            a3 = fmaf(row[d + 3], row[d + 3], a3);
        }
        csq[i] = (a0 + a1) + (a2 + a3);
    }
}

// ---------------------------------------------------------------------------
// Main: block = 256 threads = 128 queries x 2 k-halves. g = blockIdx.y.
// Waves 0,1 scan k=0..127; waves 2,3 scan k=128..255; LDS merge (ties ->
// lower half) reproduces the ascending strict-< scan exactly.
// Epilogue writes the [128][64] x_q tile coalesced (16 lanes per row) and
// accumulates the loss.
// ---------------------------------------------------------------------------
__global__ __launch_bounds__(256, 4) void pq_main(const float* __restrict__ x,
                                                  const float* __restrict__ cb,
                                                  const float* __restrict__ csq,
                                                  float* __restrict__ out) {
    const int g = blockIdx.y;
    const int t = threadIdx.x;
    const int kh = __builtin_amdgcn_readfirstlane(t >> 7);  // wave-uniform 0/1
    const int ql = t & (QB - 1);
    const int q0 = blockIdx.x * QB;
    const int bt = q0 + ql;

    __shared__ float m_d[QB];
    __shared__ int   m_i[QB];
    __shared__ float wsum[4];

    const float* xrow = x + (size_t)bt * DIM + g * GD;
    float4 xr[16];
#pragma unroll
    for (int i = 0; i < 16; ++i) xr[i] = ((const float4*)xrow)[i];

    // x_sq, canonical stride-4 pattern (matches the passing kernel exactly)
    float a0 = 0.f, a1 = 0.f, a2 = 0.f, a3 = 0.f;
#pragma unroll
    for (int i = 0; i < 16; ++i) {
        a0 = fmaf(xr[i].x, xr[i].x, a0);
        a1 = fmaf(xr[i].y, xr[i].y, a1);
        a2 = fmaf(xr[i].z, xr[i].z, a2);
        a3 = fmaf(xr[i].w, xr[i].w, a3);
    }
    const float x_sq = (a0 + a1) + (a2 + a3);

    const float* cbg = cb + (size_t)g * NK * GD;
    const float* csqg = csq + g * NK;

    const int kbase = kh << 7;  // 0 or 128, wave-uniform
    float best = 3.402823466e38f;
    int bi = kbase;
#pragma unroll 2
    for (int kk = 0; kk < 128; ++kk) {
        const int k = kbase + kk;
        const float4* c4 = (const float4*)(cbg + k * GD);
        float d0 = 0.f, d1 = 0.f, d2 = 0.f, d3 = 0.f;
#pragma unroll
        for (int i = 0; i < 16; ++i) {
            float4 c = c4[i];
            d0 = fmaf(xr[i].x, c.x, d0);
            d1 = fmaf(xr[i].y, c.y, d1);
            d2 = fmaf(xr[i].z, c.z, d2);
            d3 = fmaf(xr[i].w, c.w, d3);
        }
        float dot = (d0 + d1) + (d2 + d3);
        float dist = (x_sq + csqg[k]) - 2.0f * dot;
        if (dist < best) { best = dist; bi = k; }
    }

    // merge the two halves: prefer the lower half on exact ties
    if (kh == 1) { m_d[ql] = best; m_i[ql] = bi; }
    __syncthreads();
    if (kh == 0) {
        float dh = m_d[ql];
        int ih = m_i[ql];
        if (dh < best) { best = dh; bi = ih; }
        m_i[ql] = bi;  // final winner for the epilogue
        out[IDX_OFF + (size_t)bt * NG + g] = (float)bi;
    }
    __syncthreads();

    // --- epilogue: coalesced x_q tile write + loss partial ---
    // 16 lanes per row (64 floats = 16 float4), 16 rows per pass, 8 passes
    const int r_off = t >> 4;   // 0..15
    const int c4i = t & 15;     // float4 column
    float s0 = 0.f, s1 = 0.f, s2 = 0.f, s3 = 0.f;
#pragma unroll
    for (int p = 0; p < 8; ++p) {
        const int r = p * 16 + r_off;
        const int code = m_i[r];
        const size_t base = (size_t)(q0 + r) * DIM + g * GD + c4i * 4;
        float4 x4 = *(const float4*)(x + base);
        float4 q4 = *(const float4*)(cbg + code * GD + c4i * 4);
        float dx = q4.x - x4.x;
        float dy = q4.y - x4.y;
        float dz = q4.z - x4.z;
        float dw = q4.w - x4.w;
        float4 o;
        o.x = x4.x + dx;
        o.y = x4.y + dy;
        o.z = x4.z + dz;
        o.w = x4.w + dw;
        *(float4*)(out + base) = o;
        s0 = fmaf(dx, dx, s0);
        s1 = fmaf(dy, dy, s1);
        s2 = fmaf(dz, dz, s2);
        s3 = fmaf(dw, dw, s3);
    }
    float part = (s0 + s1) + (s2 + s3);

    // wave reduce (64 lanes)
#pragma unroll
    for (int off = 32; off > 0; off >>= 1) part += __shfl_down(part, off);

    const int lane = t & 63;
    const int wid = t >> 6;
    if (lane == 0) wsum[wid] = part;
    __syncthreads();
    if (t == 0) {
        float bs = (wsum[0] + wsum[1]) + (wsum[2] + wsum[3]);
        // losses = 2 * sum_g mean_{B,T,gd}; divisor = 32768*64 = 2097152
        atomicAdd(out + LOSS_OFF, bs * (2.0f / 2097152.0f));
    }
}

extern "C" void kernel_launch(void* const* d_in, const int* in_sizes, int n_in,
                              void* d_out, int out_size, void* d_ws, size_t ws_size,
                              hipStream_t stream) {
    const float* x = (const float*)d_in[0];
    const float* cb = (const float*)d_in[1];
    float* out = (float*)d_out;
    float* csq = (float*)d_ws;  // 2048 floats = 8 KB scratch

    pq_prep<<<dim3(8), dim3(256), 0, stream>>>(cb, csq, out + LOSS_OFF);

    dim3 grid(BT_TOTAL / QB, NG);   // (256, 8) = 2048 blocks
    pq_main<<<grid, dim3(256), 0, stream>>>(x, cb, csq, out);
}

// Round 3
// 144.734 us; speedup vs baseline: 1.0205x; 1.0190x over previous
//
#include <hip/hip_runtime.h>

// Problem constants
#define BT_TOTAL (32 * 1024)   // B*T = 32768
#define DIM 512                // D
#define NG 8                   // G groups
#define NK 256                 // K codes per group
#define GD 64                  // group dim

#define QB 128                 // queries per block
#define CCH 64                 // codes per chunk
#define NCH 4                  // chunks (4*64 = 256)

#define XT_STRIDE 65           // padded (bank-conflict-free: 65 % 32 == 1)
#define CT_STRIDE 68           // padded, 16B-aligned rows (68*4 = 272, %16==0)

#define XQ_ELEMS (BT_TOTAL * DIM)          // 16777216
#define LOSS_OFF XQ_ELEMS                  // 16777216
#define IDX_OFF (XQ_ELEMS + 1)             // 16777217

// ---------------------------------------------------------------------------
// Prep: c_sq[g][k] = sum_d cb[g][k][d]^2 (canonical stride-4 order), zero loss
// ---------------------------------------------------------------------------
__global__ void pq_prep(const float* __restrict__ cb,
                        float* __restrict__ csq,
                        float* __restrict__ loss_slot) {
    int i = blockIdx.x * 256 + threadIdx.x;  // 0 .. 2047
    if (i == 0) *loss_slot = 0.0f;
    if (i < NG * NK) {
        const float* row = cb + (size_t)i * GD;
        float a0 = 0.f, a1 = 0.f, a2 = 0.f, a3 = 0.f;
#pragma unroll
        for (int d = 0; d < GD; d += 4) {
            a0 = fmaf(row[d + 0], row[d + 0], a0);
            a1 = fmaf(row[d + 1], row[d + 1], a1);
            a2 = fmaf(row[d + 2], row[d + 2], a2);
            a3 = fmaf(row[d + 3], row[d + 3], a3);
        }
        csq[i] = (a0 + a1) + (a2 + a3);
    }
}

// ---------------------------------------------------------------------------
// Main: register-blocked GEMM-style distance computation.
// Block: 256 threads = ty(32) x tx(8); thread tile = 4 queries x 8 codes.
// xt[128 q][65] in LDS; ct[64 d][68] transposed code chunk in LDS.
// ---------------------------------------------------------------------------
__global__ __launch_bounds__(256, 3) void pq_main(const float* __restrict__ x,
                                                  const float* __restrict__ cb,
                                                  const float* __restrict__ csq,
                                                  float* __restrict__ out) {
    const int g = blockIdx.y;
    const int t = threadIdx.x;
    const int q0 = blockIdx.x * QB;

    __shared__ __align__(16) float ct[GD * CT_STRIDE];   // 17408 B (aliased as red later)
    __shared__ __align__(16) float xt[QB * XT_STRIDE];   // 33280 B
    __shared__ float xsq[QB];
    __shared__ int   m_i[QB];
    __shared__ float wsum[4];

    const float* cbg = cb + (size_t)g * NK * GD;
    const float* csqg = csq + g * NK;
    const float* xg = x + (size_t)q0 * DIM + g * GD;

    // ---- stage xt: 128 q x 16 float4, 8 per thread, coalesced reads ----
#pragma unroll
    for (int j = 0; j < 8; ++j) {
        int flat = t + j * 256;       // 0..2047
        int q = flat >> 4;            // 0..127
        int dv = flat & 15;           // float4 index over d
        float4 v = *(const float4*)(xg + (size_t)q * DIM + dv * 4);
        float* w = &xt[q * XT_STRIDE + dv * 4];
        w[0] = v.x; w[1] = v.y; w[2] = v.z; w[3] = v.w;
    }
    // ---- stage ct chunk 0: 64 codes x 16 float4, 4 per thread ----
#pragma unroll
    for (int j = 0; j < 4; ++j) {
        int flat = t + j * 256;       // 0..1023
        int c = flat >> 4;            // 0..63
        int dv = flat & 15;
        float4 v = *(const float4*)(cbg + (size_t)c * GD + dv * 4);
        ct[(dv * 4 + 0) * CT_STRIDE + c] = v.x;
        ct[(dv * 4 + 1) * CT_STRIDE + c] = v.y;
        ct[(dv * 4 + 2) * CT_STRIDE + c] = v.z;
        ct[(dv * 4 + 3) * CT_STRIDE + c] = v.w;
    }
    // ---- x_sq from GLOBAL x (no race with xt staging), round-1 pattern ----
    if (t < QB) {
        const float4* xr4 = (const float4*)(xg + (size_t)t * DIM);
        float a0 = 0.f, a1 = 0.f, a2 = 0.f, a3 = 0.f;
#pragma unroll
        for (int i = 0; i < 16; ++i) {
            float4 v = xr4[i];
            a0 = fmaf(v.x, v.x, a0);
            a1 = fmaf(v.y, v.y, a1);
            a2 = fmaf(v.z, v.z, a2);
            a3 = fmaf(v.w, v.w, a3);
        }
        xsq[t] = (a0 + a1) + (a2 + a3);
    }
    __syncthreads();

    const int tx = t & 7;    // code sub-tile
    const int ty = t >> 3;   // query sub-tile (0..31)
    const int qb = ty * 4;   // first of 4 queries

    float best[4], bidx_f;
    int bidx[4];
#pragma unroll
    for (int j = 0; j < 4; ++j) { best[j] = 3.402823466e38f; bidx[j] = 0; }
    (void)bidx_f;

    for (int ch = 0; ch < NCH; ++ch) {
        const int c0 = ch * CCH;
        float acc[4][8];
#pragma unroll
        for (int j = 0; j < 4; ++j)
#pragma unroll
            for (int i = 0; i < 8; ++i) acc[j][i] = 0.f;

        const float* xrow = &xt[qb * XT_STRIDE];
        const float* cbase = &ct[tx * 8];
#pragma unroll 8
        for (int d = 0; d < GD; ++d) {
            float xv0 = xrow[0 * XT_STRIDE + d];
            float xv1 = xrow[1 * XT_STRIDE + d];
            float xv2 = xrow[2 * XT_STRIDE + d];
            float xv3 = xrow[3 * XT_STRIDE + d];
            float4 cA = *(const float4*)(cbase + d * CT_STRIDE);
            float4 cB = *(const float4*)(cbase + d * CT_STRIDE + 4);
            acc[0][0] = fmaf(xv0, cA.x, acc[0][0]);
            acc[0][1] = fmaf(xv0, cA.y, acc[0][1]);
            acc[0][2] = fmaf(xv0, cA.z, acc[0][2]);
            acc[0][3] = fmaf(xv0, cA.w, acc[0][3]);
            acc[0][4] = fmaf(xv0, cB.x, acc[0][4]);
            acc[0][5] = fmaf(xv0, cB.y, acc[0][5]);
            acc[0][6] = fmaf(xv0, cB.z, acc[0][6]);
            acc[0][7] = fmaf(xv0, cB.w, acc[0][7]);
            acc[1][0] = fmaf(xv1, cA.x, acc[1][0]);
            acc[1][1] = fmaf(xv1, cA.y, acc[1][1]);
            acc[1][2] = fmaf(xv1, cA.z, acc[1][2]);
            acc[1][3] = fmaf(xv1, cA.w, acc[1][3]);
            acc[1][4] = fmaf(xv1, cB.x, acc[1][4]);
            acc[1][5] = fmaf(xv1, cB.y, acc[1][5]);
            acc[1][6] = fmaf(xv1, cB.z, acc[1][6]);
            acc[1][7] = fmaf(xv1, cB.w, acc[1][7]);
            acc[2][0] = fmaf(xv2, cA.x, acc[2][0]);
            acc[2][1] = fmaf(xv2, cA.y, acc[2][1]);
            acc[2][2] = fmaf(xv2, cA.z, acc[2][2]);
            acc[2][3] = fmaf(xv2, cA.w, acc[2][3]);
            acc[2][4] = fmaf(xv2, cB.x, acc[2][4]);
            acc[2][5] = fmaf(xv2, cB.y, acc[2][5]);
            acc[2][6] = fmaf(xv2, cB.z, acc[2][6]);
            acc[2][7] = fmaf(xv2, cB.w, acc[2][7]);
            acc[3][0] = fmaf(xv3, cA.x, acc[3][0]);
            acc[3][1] = fmaf(xv3, cA.y, acc[3][1]);
            acc[3][2] = fmaf(xv3, cA.z, acc[3][2]);
            acc[3][3] = fmaf(xv3, cA.w, acc[3][3]);
            acc[3][4] = fmaf(xv3, cB.x, acc[3][4]);
            acc[3][5] = fmaf(xv3, cB.y, acc[3][5]);
            acc[3][6] = fmaf(xv3, cB.z, acc[3][6]);
            acc[3][7] = fmaf(xv3, cB.w, acc[3][7]);
        }

        // argmin update (codes ascending within thread; chunks ascending)
#pragma unroll
        for (int j = 0; j < 4; ++j) {
            float xs = xsq[qb + j];
#pragma unroll
            for (int i = 0; i < 8; ++i) {
                int k = c0 + tx * 8 + i;
                float dist = (xs + csqg[k]) - 2.0f * acc[j][i];
                if (dist < best[j]) { best[j] = dist; bidx[j] = k; }
            }
        }

        __syncthreads();  // everyone done reading ct
        if (ch < NCH - 1) {
            const int c0n = (ch + 1) * CCH;
#pragma unroll
            for (int j = 0; j < 4; ++j) {
                int flat = t + j * 256;
                int c = flat >> 4;
                int dv = flat & 15;
                float4 v = *(const float4*)(cbg + (size_t)(c0n + c) * GD + dv * 4);
                ct[(dv * 4 + 0) * CT_STRIDE + c] = v.x;
                ct[(dv * 4 + 1) * CT_STRIDE + c] = v.y;
                ct[(dv * 4 + 2) * CT_STRIDE + c] = v.z;
                ct[(dv * 4 + 3) * CT_STRIDE + c] = v.w;
            }
            __syncthreads();
        }
    }

    // ---- cross-thread argmin merge (red aliased onto ct, which is free) ----
    float* red_d = ct;                       // [8 tx][128 q]  4 KB
    int*   red_i = (int*)(ct + 8 * QB);      // [8 tx][128 q]  4 KB
#pragma unroll
    for (int j = 0; j < 4; ++j) {
        red_d[tx * QB + qb + j] = best[j];
        red_i[tx * QB + qb + j] = bidx[j];
    }
    __syncthreads();
    if (t < QB) {
        float b = red_d[t];
        int bi = red_i[t];
#pragma unroll
        for (int s = 1; s < 8; ++s) {
            float v = red_d[s * QB + t];
            int vi = red_i[s * QB + t];
            // lexicographic (dist, index): exact first-min semantics
            if (v < b || (v == b && vi < bi)) { b = v; bi = vi; }
        }
        m_i[t] = bi;
        out[IDX_OFF + (size_t)(q0 + t) * NG + g] = (float)bi;
    }
    __syncthreads();

    // ---- epilogue: coalesced x_q writes (x from xt) + loss partial ----
    const int r_off = t >> 4;   // 0..15
    const int c4i = t & 15;     // float4 column
    float s0 = 0.f, s1 = 0.f, s2 = 0.f, s3 = 0.f;
#pragma unroll
    for (int p = 0; p < 8; ++p) {
        const int r = p * 16 + r_off;
        const int code = m_i[r];
        const float* xls = &xt[r * XT_STRIDE + c4i * 4];
        float x0 = xls[0], x1 = xls[1], x2 = xls[2], x3 = xls[3];
        float4 q4 = *(const float4*)(cbg + (size_t)code * GD + c4i * 4);
        float dx = q4.x - x0;
        float dy = q4.y - x1;
        float dz = q4.z - x2;
        float dw = q4.w - x3;
        float4 o;
        o.x = x0 + dx;
        o.y = x1 + dy;
        o.z = x2 + dz;
        o.w = x3 + dw;
        *(float4*)(out + (size_t)(q0 + r) * DIM + g * GD + c4i * 4) = o;
        s0 = fmaf(dx, dx, s0);
        s1 = fmaf(dy, dy, s1);
        s2 = fmaf(dz, dz, s2);
        s3 = fmaf(dw, dw, s3);
    }
    float part = (s0 + s1) + (s2 + s3);

#pragma unroll
    for (int off = 32; off > 0; off >>= 1) part += __shfl_down(part, off);

    const int lane = t & 63;
    const int wid = t >> 6;
    if (lane == 0) wsum[wid] = part;
    __syncthreads();
    if (t == 0) {
        float bs = (wsum[0] + wsum[1]) + (wsum[2] + wsum[3]);
        atomicAdd(out + LOSS_OFF, bs * (2.0f / 2097152.0f));
    }
}

extern "C" void kernel_launch(void* const* d_in, const int* in_sizes, int n_in,
                              void* d_out, int out_size, void* d_ws, size_t ws_size,
                              hipStream_t stream) {
    const float* x = (const float*)d_in[0];
    const float* cb = (const float*)d_in[1];
    float* out = (float*)d_out;
    float* csq = (float*)d_ws;  // 2048 floats = 8 KB scratch

    pq_prep<<<dim3(8), dim3(256), 0, stream>>>(cb, csq, out + LOSS_OFF);

    dim3 grid(BT_TOTAL / QB, NG);   // (256, 8) = 2048 blocks
    pq_main<<<grid, dim3(256), 0, stream>>>(x, cb, csq, out);
}

// Round 4
// 129.826 us; speedup vs baseline: 1.1377x; 1.1148x over previous
//
#include <hip/hip_runtime.h>

// Problem constants
#define BT_TOTAL (32 * 1024)   // B*T = 32768
#define DIM 512                // D
#define NG 8                   // G groups
#define NK 256                 // K codes per group
#define GD 64                  // group dim
#define QB 256                 // queries per block

#define XQ_ELEMS (BT_TOTAL * DIM)          // 16777216
#define LOSS_OFF XQ_ELEMS                  // 16777216
#define IDX_OFF (XQ_ELEMS + 1)             // 16777217

typedef float f32x16 __attribute__((ext_vector_type(16)));

// ---------------------------------------------------------------------------
// Prep: c_sq[g][k] = sum_d cb[g][k][d]^2 (canonical stride-4 order), zero loss
// ---------------------------------------------------------------------------
__global__ void pq_prep(const float* __restrict__ cb,
                        float* __restrict__ csq,
                        float* __restrict__ loss_slot) {
    int i = blockIdx.x * 256 + threadIdx.x;  // 0 .. 2047
    if (i == 0) *loss_slot = 0.0f;
    if (i < NG * NK) {
        const float* row = cb + (size_t)i * GD;
        float a0 = 0.f, a1 = 0.f, a2 = 0.f, a3 = 0.f;
#pragma unroll
        for (int d = 0; d < GD; d += 4) {
            a0 = fmaf(row[d + 0], row[d + 0], a0);
            a1 = fmaf(row[d + 1], row[d + 1], a1);
            a2 = fmaf(row[d + 2], row[d + 2], a2);
            a3 = fmaf(row[d + 3], row[d + 3], a3);
        }
        csq[i] = (a0 + a1) + (a2 + a3);
    }
}

// ---------------------------------------------------------------------------
// Main: one thread per (bt, g); x row resident in 64 VGPRs; codes streamed
// through SGPRs via s_load_dwordx16 (wave-uniform broadcast — no LDS, no
// vector loads in the k-loop). Full ascending strict-< argmin per thread.
// ---------------------------------------------------------------------------
__global__ __launch_bounds__(256, 4) void pq_main(const float* __restrict__ x,
                                                  const float* __restrict__ cb,
                                                  const float* __restrict__ csq,
                                                  float* __restrict__ out) {
    const int g = blockIdx.y;
    const int t = threadIdx.x;
    const int q0 = blockIdx.x * QB;
    const int bt = q0 + t;

    __shared__ int   m_i[QB];
    __shared__ float wsum[4];

    const float* cbg = cb + (size_t)g * NK * GD;
    const float* csqg = csq + g * NK;

    // x row -> 64 VGPRs
    const float* xrow = x + (size_t)bt * DIM + g * GD;
    float4 xr[16];
#pragma unroll
    for (int i = 0; i < 16; ++i) xr[i] = ((const float4*)xrow)[i];

    // x_sq, canonical stride-4 pattern (bit-matches rounds 1-3)
    float a0 = 0.f, a1 = 0.f, a2 = 0.f, a3 = 0.f;
#pragma unroll
    for (int i = 0; i < 16; ++i) {
        a0 = fmaf(xr[i].x, xr[i].x, a0);
        a1 = fmaf(xr[i].y, xr[i].y, a1);
        a2 = fmaf(xr[i].z, xr[i].z, a2);
        a3 = fmaf(xr[i].w, xr[i].w, a3);
    }
    const float x_sq = (a0 + a1) + (a2 + a3);

    float best = 3.402823466e38f;
    int bi = 0;

#pragma unroll 1
    for (int k = 0; k < NK; ++k) {
        f32x16 c0, c1, c2, c3;
        float cs;
        const float* ck = cbg + (size_t)k * GD;
        const float* pk = csqg + k;
        // wave-uniform scalar loads: one 256B code row + its c_sq
        asm volatile(
            "s_load_dwordx16 %0, %5, 0x0\n\t"
            "s_load_dwordx16 %1, %5, 0x40\n\t"
            "s_load_dwordx16 %2, %5, 0x80\n\t"
            "s_load_dwordx16 %3, %5, 0xc0\n\t"
            "s_load_dword    %4, %6, 0x0"
            : "=s"(c0), "=s"(c1), "=s"(c2), "=s"(c3), "=s"(cs)
            : "s"(ck), "s"(pk));
        // waitcnt with tied operands: uses of c0..cs below data-depend on it
        asm volatile("s_waitcnt lgkmcnt(0)"
                     : "+s"(c0), "+s"(c1), "+s"(c2), "+s"(c3), "+s"(cs));

        // dot, dims ascending, accumulator = dim%4 (bit-matches rounds 1-3)
        float d0 = 0.f, d1 = 0.f, d2 = 0.f, d3 = 0.f;
#define Q4(cv, i4, b)                              \
        d0 = fmaf(cv[(i4) * 4 + 0], xr[b].x, d0);  \
        d1 = fmaf(cv[(i4) * 4 + 1], xr[b].y, d1);  \
        d2 = fmaf(cv[(i4) * 4 + 2], xr[b].z, d2);  \
        d3 = fmaf(cv[(i4) * 4 + 3], xr[b].w, d3);
        Q4(c0, 0, 0)  Q4(c0, 1, 1)  Q4(c0, 2, 2)  Q4(c0, 3, 3)
        Q4(c1, 0, 4)  Q4(c1, 1, 5)  Q4(c1, 2, 6)  Q4(c1, 3, 7)
        Q4(c2, 0, 8)  Q4(c2, 1, 9)  Q4(c2, 2, 10) Q4(c2, 3, 11)
        Q4(c3, 0, 12) Q4(c3, 1, 13) Q4(c3, 2, 14) Q4(c3, 3, 15)
#undef Q4
        float dot = (d0 + d1) + (d2 + d3);
        float dist = (x_sq + cs) - 2.0f * dot;
        if (dist < best) { best = dist; bi = k; }
    }

    m_i[t] = bi;
    out[IDX_OFF + (size_t)bt * NG + g] = (float)bi;
    __syncthreads();

    // ---- epilogue: coalesced x_q writes + loss partial (round-2 pattern) ----
    const int r_off = t >> 4;   // 0..15
    const int c4i = t & 15;     // float4 column
    float s0 = 0.f, s1 = 0.f, s2 = 0.f, s3 = 0.f;
#pragma unroll
    for (int p = 0; p < 16; ++p) {
        const int r = p * 16 + r_off;
        const int code = m_i[r];
        const size_t base = (size_t)(q0 + r) * DIM + g * GD + c4i * 4;
        float4 x4 = *(const float4*)(x + base);
        float4 q4 = *(const float4*)(cbg + (size_t)code * GD + c4i * 4);
        float dx = q4.x - x4.x;
        float dy = q4.y - x4.y;
        float dz = q4.z - x4.z;
        float dw = q4.w - x4.w;
        float4 o;
        o.x = x4.x + dx;
        o.y = x4.y + dy;
        o.z = x4.z + dz;
        o.w = x4.w + dw;
        *(float4*)(out + base) = o;
        s0 = fmaf(dx, dx, s0);
        s1 = fmaf(dy, dy, s1);
        s2 = fmaf(dz, dz, s2);
        s3 = fmaf(dw, dw, s3);
    }
    float part = (s0 + s1) + (s2 + s3);

    // wave reduce (64 lanes)
#pragma unroll
    for (int off = 32; off > 0; off >>= 1) part += __shfl_down(part, off);

    const int lane = t & 63;
    const int wid = t >> 6;
    if (lane == 0) wsum[wid] = part;
    __syncthreads();
    if (t == 0) {
        float bs = (wsum[0] + wsum[1]) + (wsum[2] + wsum[3]);
        // losses = 2 * sum_g mean_{B,T,gd}; divisor = 32768*64 = 2097152
        atomicAdd(out + LOSS_OFF, bs * (2.0f / 2097152.0f));
    }
}

extern "C" void kernel_launch(void* const* d_in, const int* in_sizes, int n_in,
                              void* d_out, int out_size, void* d_ws, size_t ws_size,
                              hipStream_t stream) {
    const float* x = (const float*)d_in[0];
    const float* cb = (const float*)d_in[1];
    float* out = (float*)d_out;
    float* csq = (float*)d_ws;  // 2048 floats = 8 KB scratch

    pq_prep<<<dim3(8), dim3(256), 0, stream>>>(cb, csq, out + LOSS_OFF);

    dim3 grid(BT_TOTAL / QB, NG);   // (128, 8) = 1024 blocks
    pq_main<<<grid, dim3(256), 0, stream>>>(x, cb, csq, out);
}